// Round 8
// baseline (916.738 us; speedup 1.0000x reference)
//
#include <hip/hip_runtime.h>
#include <math.h>

#define B_ 16
#define W_ 512
#define H_ 512
#define S_ (W_*H_)
#define ALPHA_ 0.15f
#define MU_ 10.0f
#define TAU_ 0.125f
#define SIG_ 0.125f
#define EPS_ 1e-6f
#define INV1PT_ (1.0f/(1.0f+TAU_))
#define NBINS 65536
#define BINSCALE 32768.0f
#define BINW (1.0f/32768.0f)

// ---- K1: horizontal 31-tap max via log-tree sliding max ----
__global__ __launch_bounds__(256) void hmax_kernel(const float* __restrict__ Iy,
                                                   float* __restrict__ Rh,
                                                   float* __restrict__ GBh){
  __shared__ float bufA[2][544], bufB[2][544];
  int t = threadIdx.x;
  int b = blockIdx.x >> 9;
  int i = blockIdx.x & 511;
  const float* row = Iy + (size_t)b*3*S_ + (size_t)i*W_;
  for (int p = t; p < 544; p += 256){
    int idx = p - 16;
    bool v = (idx >= 0) && (idx < 512);
    bufA[0][p] = v ? row[idx] : -1e30f;
    bufA[1][p] = v ? fmaxf(row[S_+idx], row[2*S_+idx]) : -1e30f;
  }
  __syncthreads();
  float (*src)[544] = bufA; float (*dst)[544] = bufB;
  const int ds[5] = {1, 2, 4, 8, 15};
  #pragma unroll
  for (int sstep = 0; sstep < 5; ++sstep){
    int d = ds[sstep];
    for (int p = t; p < 544; p += 256){
      int q = min(p + d, 543);
      dst[0][p] = fmaxf(src[0][p], src[0][q]);
      dst[1][p] = fmaxf(src[1][p], src[1][q]);
    }
    __syncthreads();
    float (*tmp)[544] = src; src = dst; dst = tmp;
  }
  size_t o = (size_t)b*S_ + (size_t)i*W_;
  for (int p = t; p < 512; p += 256){
    Rh[o+p]  = src[0][p+1];
    GBh[o+p] = src[1][p+1];
  }
}

// ---- vertical van Herk forward scan ----
__global__ __launch_bounds__(256) void vscan_fwd_kernel(const float* __restrict__ Rh,
                                                        const float* __restrict__ GBh,
                                                        float* __restrict__ Rf,
                                                        float* __restrict__ Gf){
  int gid = blockIdx.x*256 + threadIdx.x;
  int col = gid & 8191;
  int c   = gid >> 13;
  int b = col >> 9, j = col & 511;
  int i0 = c*62, i1 = (c==8) ? 512 : i0+62;
  size_t base = (size_t)b*S_ + j;
  float rR = -1e30f, rG = -1e30f;
  int m = 0;
  for (int i = i0; i < i1; ++i){
    size_t o = base + (size_t)i*W_;
    float vR = Rh[o], vG = GBh[o];
    if (m == 0){ rR = vR; rG = vG; }
    else       { rR = fmaxf(rR, vR); rG = fmaxf(rG, vG); }
    Rf[o] = rR; Gf[o] = rG;
    m = (m==30) ? 0 : m+1;
  }
}

// ---- vertical bwd scan; x = |Rmax - GBmax| + R (no histogramming) ----
__global__ __launch_bounds__(256) void vscan_bwd_kernel(const float* __restrict__ Rh,
                                                        const float* __restrict__ GBh,
                                                        const float* __restrict__ Rf,
                                                        const float* __restrict__ Gf,
                                                        const float* __restrict__ Iy,
                                                        float* __restrict__ xo){
  int gid = blockIdx.x*256 + threadIdx.x;
  int col = gid & 8191;
  int c   = gid >> 13;
  int b = col >> 9, j = col & 511;
  int i0 = c*62, i1 = (c==8) ? 512 : i0+62;
  size_t base = (size_t)b*S_ + j;
  const float* IyR = Iy + (size_t)b*3*S_ + j;
  float lR = -1e30f, lG = -1e30f;
  int m = (c==8) ? 15 : 30;
  for (int i = i1-1; i >= i0; --i){
    size_t o64 = base + (size_t)i*W_;
    float vR = Rh[o64], vG = GBh[o64];
    if (m == 30){ lR = vR; lG = vG; }
    else        { lR = fmaxf(lR, vR); lG = fmaxf(lG, vG); }
    int o = i + 15;
    if (o < 512){
      int bi = min(i + 30, 511);
      size_t ob = base + (size_t)bi*W_;
      float mR = fmaxf(lR, Rf[ob]);
      float mG = fmaxf(lG, Gf[ob]);
      xo[base + (size_t)o*W_] = fabsf(mR - mG) + IyR[(size_t)o*W_];
    }
    m = (m==0) ? 30 : m-1;
  }
  if (c == 0){
    for (int o = 0; o < 15; ++o){
      size_t ob = base + (size_t)(o+15)*W_;
      float mR = Rf[ob], mG = Gf[ob];
      xo[base + (size_t)o*W_] = fabsf(mR - mG) + IyR[(size_t)o*W_];
    }
  }
}

// ---- build a 65536-bin per-batch histogram of a [0,2) buffer ----
__global__ __launch_bounds__(256) void hist_build_kernel(const float* __restrict__ data,
                                                         unsigned int* __restrict__ hist){
  int t = threadIdx.x;
  int b = blockIdx.x >> 4, sub = blockIdx.x & 15;
  const float* p = data + (size_t)b*S_ + (size_t)sub*16384;
  unsigned int* hb = hist + (size_t)b*NBINS;
  for (int k = 0; k < 64; ++k){
    float x = p[k*256 + t];
    int bin = (int)(x*BINSCALE);
    if (bin > NBINS-1) bin = NBINS-1;
    if (bin < 0) bin = 0;
    atomicAdd(&hb[bin], 1u);
  }
}

// ---- pick order statistics from a 65536-bin histogram; one block/batch ----
__global__ __launch_bounds__(256) void pick_hist_kernel(
    const unsigned int* __restrict__ hist, int r0, int r1, int r2, int r3,
    int nranks, float* __restrict__ outv, int which){
  __shared__ unsigned int part[256];
  __shared__ int s_own[4], s_rem[4];
  __shared__ float s_val[4];
  int t = threadIdx.x, b = blockIdx.x;
  const unsigned int* hb = hist + (size_t)b*NBINS + t*256;
  unsigned int sum = 0u;
  for (int k = 0; k < 256; ++k) sum += hb[k];
  part[t] = sum;
  __syncthreads();
  if (t == 0){
    int rk[4] = {r0, r1, r2, r3};
    for (int ri = 0; ri < nranks; ++ri){
      int rem = rk[ri]; int own = 255;
      for (int q = 0; q < 256; ++q){
        if ((unsigned int)rem < part[q]){ own = q; break; }
        rem -= (int)part[q];
      }
      s_own[ri] = own; s_rem[ri] = rem;
    }
  }
  __syncthreads();
  for (int ri = 0; ri < nranks; ++ri){
    if (t == s_own[ri]){
      int rem = s_rem[ri]; int bin = t*256 + 255;
      for (int q = 0; q < 256; ++q){
        unsigned int hv = hb[q];
        if ((unsigned int)rem < hv){ bin = t*256 + q; break; }
        rem -= (int)hv;
      }
      s_val[ri] = ((float)bin + 0.5f) * BINW;
    }
  }
  __syncthreads();
  if (t == 0){
    if (which == 0){
      outv[2*b+0] = s_val[0]*0.57f + s_val[1]*0.43f;   // lo (pos frac .43)
      outv[2*b+1] = s_val[2]*0.43f + s_val[3]*0.57f;   // hi (pos frac .57)
    } else {
      outv[b] = fmaxf(0.5f*(s_val[0] + s_val[1]), EPS_); // median -> sigma
    }
  }
}

// ---- N_hat + grad_mag (both stored) ----
__global__ __launch_bounds__(256) void nhat_gm_kernel(const float* __restrict__ x,
                                                      const float* __restrict__ vx2,
                                                      float* __restrict__ nh,
                                                      float* __restrict__ gm){
  int j = blockIdx.x*64 + threadIdx.x;
  int i = blockIdx.y*4 + threadIdx.y;
  int b = blockIdx.z;
  float lo = vx2[2*b], hi = vx2[2*b+1];
  float inv = 1.0f/(hi - lo + EPS_);
  size_t base = (size_t)b*S_ + (size_t)i*W_ + j;
  float c = fminf(fmaxf((x[base] - lo)*inv, 0.f), 1.f);
  float dx = 0.f, dy = 0.f;
  if (j < W_-1) dx = fminf(fmaxf((x[base+1]  - lo)*inv, 0.f), 1.f) - c;
  if (i < H_-1) dy = fminf(fmaxf((x[base+W_] - lo)*inv, 0.f), 1.f) - c;
  nh[base] = c;
  gm[base] = sqrtf(dx*dx + dy*dy + EPS_);
}

// ---- fused T-iteration primal-dual (hardware-proven version, verbatim) ----
#define TILE 48
#define NPIX (TILE*TILE)
#define CORE 32
#define HALO 8

#define AW_(d) (ALPHA_*(1.0f + MU_*__expf(-fabsf(d)*invs)))

__global__ __launch_bounds__(256, 4) void pd_fused_kernel(
    const float* __restrict__ u_in,  const float* __restrict__ ub_in,
    const float* __restrict__ px_in, const float* __restrict__ py_in,
    float* __restrict__ u_out,  float* __restrict__ ub_out,
    float* __restrict__ px_out, float* __restrict__ py_out,
    const float* __restrict__ nh_g, const float* __restrict__ sig_arr,
    int T, int mode)   // mode 1 = init from nh; 2 = last launch (store u only)
{
  __shared__ float sA[NPIX], sB[NPIX];
  const int t = threadIdx.x;
  const int b = blockIdx.z;
  const int gi0 = blockIdx.y*CORE - HALO;
  const int gj0 = blockIdx.x*CORE - HALO;
  const float invs = 1.0f / sig_arr[b];
  const int pi = t >> 4, pj = t & 15;
  const int r0 = 3*pi, c0 = 3*pj;
  const size_t bb = (size_t)b*S_;

  #define STAGE(dst, srcP, ZOOB)                                   \
    _Pragma("unroll")                                              \
    for (int k = 0; k < 9; ++k){                                   \
      int p = t + k*256; int li = p/TILE, lj = p - li*TILE;        \
      int gi = gi0+li, gj = gj0+lj;                                \
      int gic = min(max(gi,0),H_-1), gjc = min(max(gj,0),W_-1);    \
      float v = srcP[bb + (size_t)gic*W_ + gjc];                   \
      if (ZOOB && ((gi != gic) || (gj != gjc))) v = 0.f;           \
      dst[p] = v; }

  // Phase A: nh
  STAGE(sB, nh_g, 0)
  if (mode == 1){ STAGE(sA, nh_g, 0) }
  __syncthreads();

  float nh_r[9], ax[9], ay[9], axL[3], ayU[3];
  #pragma unroll
  for (int r = 0; r < 3; ++r)
  #pragma unroll
  for (int c = 0; c < 3; ++c){
    const int q = r*3+c, li = r0+r, lj = c0+c;
    const int gi = gi0+li, gj = gj0+lj;
    float nhc = sB[li*TILE+lj];
    float nhR = sB[li*TILE + min(lj+1,TILE-1)];
    float nhD = sB[min(li+1,TILE-1)*TILE + lj];
    nh_r[q] = nhc;
    ax[q] = (gj < 0 || gj >= W_-1) ? 0.f : AW_(nhR-nhc);
    ay[q] = (gi < 0 || gi >= H_-1) ? 0.f : AW_(nhD-nhc);
  }
  #pragma unroll
  for (int r = 0; r < 3; ++r){
    int liL = r0+r, gjL = gj0 + c0 - 1;
    int idxc = max(c0-1, 0);
    float nhc = sB[liL*TILE + idxc];
    float nhR = sB[liL*TILE + min(idxc+1,TILE-1)];
    axL[r] = (gjL < 0 || gjL >= W_-1) ? 0.f : AW_(nhR-nhc);
  }
  #pragma unroll
  for (int c = 0; c < 3; ++c){
    int giU = gi0 + r0 - 1;
    int idxr = max(r0-1, 0);
    float nhc = sB[idxr*TILE + c0+c];
    float nhD = sB[min(idxr+1,TILE-1)*TILE + c0+c];
    ayU[c] = (giU < 0 || giU >= H_-1) ? 0.f : AW_(nhD-nhc);
  }
  __syncthreads();

  float u_r[9], ub_r[9], px_r[9], py_r[9], pxL[3], pyU[3];
  if (mode == 1){
    #pragma unroll
    for (int q = 0; q < 9; ++q){ u_r[q] = nh_r[q]; ub_r[q] = nh_r[q]; px_r[q] = 0.f; py_r[q] = 0.f; }
    pxL[0]=pxL[1]=pxL[2]=0.f; pyU[0]=pyU[1]=pyU[2]=0.f;
    // sA already holds nh = initial ub
  } else {
    STAGE(sB, u_in, 0)
    __syncthreads();
    #pragma unroll
    for (int q = 0; q < 9; ++q) u_r[q] = sB[(r0+q/3)*TILE + c0 + q%3];
    __syncthreads();
    STAGE(sB, px_in, 1)
    __syncthreads();
    #pragma unroll
    for (int q = 0; q < 9; ++q) px_r[q] = sB[(r0+q/3)*TILE + c0 + q%3];
    #pragma unroll
    for (int r = 0; r < 3; ++r) pxL[r] = sB[(r0+r)*TILE + max(c0-1,0)];
    __syncthreads();
    STAGE(sB, py_in, 1)
    __syncthreads();
    #pragma unroll
    for (int q = 0; q < 9; ++q) py_r[q] = sB[(r0+q/3)*TILE + c0 + q%3];
    #pragma unroll
    for (int c = 0; c < 3; ++c) pyU[c] = sB[max(r0-1,0)*TILE + c0+c];
    __syncthreads();
    STAGE(sA, ub_in, 0)
    __syncthreads();
    #pragma unroll
    for (int q = 0; q < 9; ++q) ub_r[q] = sA[(r0+q/3)*TILE + c0 + q%3];
  }

  for (int s = 0; s < T; ++s){
    float* RB = (s & 1) ? sB : sA;
    float* WB = (s & 1) ? sA : sB;
    float ubL[3], ubR[3], ubU[3], ubD[3];
    #pragma unroll
    for (int r = 0; r < 3; ++r){
      ubL[r] = RB[(r0+r)*TILE + max(c0-1,0)];
      ubR[r] = RB[(r0+r)*TILE + min(c0+3,TILE-1)];
    }
    #pragma unroll
    for (int c = 0; c < 3; ++c){
      ubU[c] = RB[max(r0-1,0)*TILE + c0+c];
      ubD[c] = RB[min(r0+3,TILE-1)*TILE + c0+c];
    }
    #pragma unroll
    for (int r = 0; r < 3; ++r)
      pxL[r] = fminf(fmaxf(fmaf(SIG_, ub_r[r*3] - ubL[r], pxL[r]), -axL[r]), axL[r]);
    #pragma unroll
    for (int c = 0; c < 3; ++c)
      pyU[c] = fminf(fmaxf(fmaf(SIG_, ub_r[c] - ubU[c], pyU[c]), -ayU[c]), ayU[c]);
    #pragma unroll
    for (int r = 0; r < 3; ++r)
    #pragma unroll
    for (int c = 0; c < 3; ++c){
      const int q = r*3+c;
      float ubRn = (c < 2) ? ub_r[q+1] : ubR[r];
      float ubDn = (r < 2) ? ub_r[q+3] : ubD[c];
      px_r[q] = fminf(fmaxf(fmaf(SIG_, ubRn - ub_r[q], px_r[q]), -ax[q]), ax[q]);
      py_r[q] = fminf(fmaxf(fmaf(SIG_, ubDn - ub_r[q], py_r[q]), -ay[q]), ay[q]);
    }
    #pragma unroll
    for (int r = 0; r < 3; ++r)
    #pragma unroll
    for (int c = 0; c < 3; ++c){
      const int q = r*3+c;
      float pxln = (c > 0) ? px_r[q-1] : pxL[r];
      float pyun = (r > 0) ? py_r[q-3] : pyU[c];
      float div = px_r[q] + py_r[q] - pxln - pyun;
      float un = fmaf(TAU_, div + nh_r[q], u_r[q]) * INV1PT_;
      float ubn = 2.f*un - u_r[q];
      u_r[q] = un; ub_r[q] = ubn;
      WB[(r0+r)*TILE + c0+c] = ubn;
    }
    __syncthreads();
  }

  #pragma unroll
  for (int r = 0; r < 3; ++r)
  #pragma unroll
  for (int c = 0; c < 3; ++c){
    const int q = r*3+c, li = r0+r, lj = c0+c;
    if (li >= HALO && li < HALO+CORE && lj >= HALO && lj < HALO+CORE){
      size_t g = bb + (size_t)(gi0+li)*W_ + (gj0+lj);
      u_out[g] = u_r[q];
      if (mode != 2){
        ub_out[g] = ub_r[q];
        px_out[g] = px_r[q];
        py_out[g] = py_r[q];
      }
    }
  }
}

// ---- final clip ----
__global__ __launch_bounds__(256) void final_kernel(const float* __restrict__ u,
                                                    float* __restrict__ out){
  size_t idx = (size_t)blockIdx.x*256 + threadIdx.x;
  if (idx < (size_t)B_*S_) out[idx] = fminf(fmaxf(u[idx], 0.f), 1.f);
}

extern "C" void kernel_launch(void* const* d_in, const int* in_sizes, int n_in,
                              void* d_out, int out_size, void* d_ws, size_t ws_size,
                              hipStream_t stream){
  const float* Iy = (const float*)d_in[0];
  float* out = (float*)d_out;
  char* ws = (char*)d_ws;
  const size_t SLOT = (size_t)B_*S_*sizeof(float);
  float* slot[8];
  for (int q = 0; q < 8; ++q) slot[q] = (float*)(ws + (size_t)q*SLOT);
  float* vx2 = (float*)(ws + (size_t)8*SLOT);  // lo,hi per batch (32 floats)
  float* sig = vx2 + 32;                       // sigma per batch (16 floats)

  // slot lifetimes: s0 Rh->gm->pyB  s1 GBh->uA  s2 x->ubA  s3 pxA
  // s4 histograms->pyA  s5 Rf->uB  s6 Gf->ubB  s7 pxB ; nh in d_out.
  float* Rh  = slot[0];
  float* GBh = slot[1];
  float* Rf  = slot[5];
  float* Gf  = slot[6];
  float* xb  = slot[2];
  float* gm  = slot[0];
  float* nh  = out;
  float* uu[2]  = { slot[1], slot[5] };
  float* ubb[2] = { slot[2], slot[6] };
  float* pxx[2] = { slot[3], slot[7] };
  float* pyy[2] = { slot[4], slot[0] };

  // histograms inside slot4 (consumed before PD L0 writes pyy[0])
  unsigned int* hist_x  = (unsigned int*)(ws + (size_t)4*SLOT);          // 4 MiB
  unsigned int* hist_gm = hist_x + (size_t)B_*NBINS;                     // 4 MiB
  const size_t HISTBYTES = (size_t)2*B_*NBINS*sizeof(unsigned int);      // 8 MiB

  dim3 blk(64, 4, 1), grd(W_/64, H_/4, B_);

  hipMemsetAsync(hist_x, 0, HISTBYTES, stream);
  hmax_kernel<<<B_*H_, 256, 0, stream>>>(Iy, Rh, GBh);
  vscan_fwd_kernel<<<288, 256, 0, stream>>>(Rh, GBh, Rf, Gf);
  vscan_bwd_kernel<<<288, 256, 0, stream>>>(Rh, GBh, Rf, Gf, Iy, xb);
  hist_build_kernel<<<256, 256, 0, stream>>>(xb, hist_x);
  // ranks: floor/ceil of 0.01*(N-1)=2621.43 and 0.99*(N-1)=259521.57
  pick_hist_kernel<<<B_, 256, 0, stream>>>(hist_x, 2621, 2622, 259521, 259522, 4, vx2, 0);
  nhat_gm_kernel<<<grd, blk, 0, stream>>>(xb, vx2, nh, gm);
  hist_build_kernel<<<256, 256, 0, stream>>>(gm, hist_gm);
  // median ranks 131071, 131072
  pick_hist_kernel<<<B_, 256, 0, stream>>>(hist_gm, 131071, 131072, 0, 0, 2, sig, 1);

  dim3 pdg(W_/CORE, H_/CORE, B_);
  pd_fused_kernel<<<pdg, 256, 0, stream>>>(nh, nh, nh, nh,
                                           uu[0], ubb[0], pxx[0], pyy[0],
                                           nh, sig, 8, 1);
  pd_fused_kernel<<<pdg, 256, 0, stream>>>(uu[0], ubb[0], pxx[0], pyy[0],
                                           uu[1], ubb[1], pxx[1], pyy[1],
                                           nh, sig, 8, 0);
  pd_fused_kernel<<<pdg, 256, 0, stream>>>(uu[1], ubb[1], pxx[1], pyy[1],
                                           uu[0], ubb[0], pxx[0], pyy[0],
                                           nh, sig, 8, 0);
  pd_fused_kernel<<<pdg, 256, 0, stream>>>(uu[0], ubb[0], pxx[0], pyy[0],
                                           uu[1], ubb[1], pxx[1], pyy[1],
                                           nh, sig, 6, 2);

  int total = B_*S_;
  final_kernel<<<(total+255)/256, 256, 0, stream>>>(uu[1], out);
}

// Round 10
// 549.461 us; speedup vs baseline: 1.6684x; 1.6684x over previous
//
#include <hip/hip_runtime.h>
#include <math.h>

#define B_ 16
#define W_ 512
#define H_ 512
#define S_ (W_*H_)
#define ALPHA_ 0.15f
#define MU_ 10.0f
#define TAU_ 0.125f
#define SIG_ 0.125f
#define EPS_ 1e-6f
#define INV1PT_ (1.0f/(1.0f+TAU_))
#define NBINS 4096
#define BINSCALE 2048.0f
#define BINW (1.0f/2048.0f)

// ---- K1: horizontal 31-tap max via log-tree sliding max ----
__global__ __launch_bounds__(256) void hmax_kernel(const float* __restrict__ Iy,
                                                   float* __restrict__ Rh,
                                                   float* __restrict__ GBh){
  __shared__ float bufA[2][544], bufB[2][544];
  int t = threadIdx.x;
  int b = blockIdx.x >> 9;
  int i = blockIdx.x & 511;
  const float* row = Iy + (size_t)b*3*S_ + (size_t)i*W_;
  for (int p = t; p < 544; p += 256){
    int idx = p - 16;
    bool v = (idx >= 0) && (idx < 512);
    bufA[0][p] = v ? row[idx] : -1e30f;
    bufA[1][p] = v ? fmaxf(row[S_+idx], row[2*S_+idx]) : -1e30f;
  }
  __syncthreads();
  float (*src)[544] = bufA; float (*dst)[544] = bufB;
  const int ds[5] = {1, 2, 4, 8, 15};
  #pragma unroll
  for (int sstep = 0; sstep < 5; ++sstep){
    int d = ds[sstep];
    for (int p = t; p < 544; p += 256){
      int q = min(p + d, 543);
      dst[0][p] = fmaxf(src[0][p], src[0][q]);
      dst[1][p] = fmaxf(src[1][p], src[1][q]);
    }
    __syncthreads();
    float (*tmp)[544] = src; src = dst; dst = tmp;
  }
  size_t o = (size_t)b*S_ + (size_t)i*W_;
  for (int p = t; p < 512; p += 256){
    Rh[o+p]  = src[0][p+1];
    GBh[o+p] = src[1][p+1];
  }
}

// ---- vertical van Herk forward scan ----
__global__ __launch_bounds__(256) void vscan_fwd_kernel(const float* __restrict__ Rh,
                                                        const float* __restrict__ GBh,
                                                        float* __restrict__ Rf,
                                                        float* __restrict__ Gf){
  int gid = blockIdx.x*256 + threadIdx.x;
  int col = gid & 8191;
  int c   = gid >> 13;
  int b = col >> 9, j = col & 511;
  int i0 = c*62, i1 = (c==8) ? 512 : i0+62;
  size_t base = (size_t)b*S_ + j;
  float rR = -1e30f, rG = -1e30f;
  int m = 0;
  for (int i = i0; i < i1; ++i){
    size_t o = base + (size_t)i*W_;
    float vR = Rh[o], vG = GBh[o];
    if (m == 0){ rR = vR; rG = vG; }
    else       { rR = fmaxf(rR, vR); rG = fmaxf(rG, vG); }
    Rf[o] = rR; Gf[o] = rG;
    m = (m==30) ? 0 : m+1;
  }
}

// ---- vertical bwd scan; x = |Rmax - GBmax| + R ----
__global__ __launch_bounds__(256) void vscan_bwd_kernel(const float* __restrict__ Rh,
                                                        const float* __restrict__ GBh,
                                                        const float* __restrict__ Rf,
                                                        const float* __restrict__ Gf,
                                                        const float* __restrict__ Iy,
                                                        float* __restrict__ xo){
  int gid = blockIdx.x*256 + threadIdx.x;
  int col = gid & 8191;
  int c   = gid >> 13;
  int b = col >> 9, j = col & 511;
  int i0 = c*62, i1 = (c==8) ? 512 : i0+62;
  size_t base = (size_t)b*S_ + j;
  const float* IyR = Iy + (size_t)b*3*S_ + j;
  float lR = -1e30f, lG = -1e30f;
  int m = (c==8) ? 15 : 30;
  for (int i = i1-1; i >= i0; --i){
    size_t o64 = base + (size_t)i*W_;
    float vR = Rh[o64], vG = GBh[o64];
    if (m == 30){ lR = vR; lG = vG; }
    else        { lR = fmaxf(lR, vR); lG = fmaxf(lG, vG); }
    int o = i + 15;
    if (o < 512){
      int bi = min(i + 30, 511);
      size_t ob = base + (size_t)bi*W_;
      float mR = fmaxf(lR, Rf[ob]);
      float mG = fmaxf(lG, Gf[ob]);
      xo[base + (size_t)o*W_] = fabsf(mR - mG) + IyR[(size_t)o*W_];
    }
    m = (m==0) ? 30 : m-1;
  }
  if (c == 0){
    for (int o = 0; o < 15; ++o){
      size_t ob = base + (size_t)(o+15)*W_;
      float mR = Rf[ob], mG = Gf[ob];
      xo[base + (size_t)o*W_] = fabsf(mR - mG) + IyR[(size_t)o*W_];
    }
  }
}

// ---- per-block PARTIAL histograms: LDS-private build (proven pattern),
// non-atomic full store of all 4096 bins. No global atomics, no memset. ----
__global__ __launch_bounds__(256) void hist_build_kernel(const float* __restrict__ data,
                                                         unsigned int* __restrict__ hist){
  __shared__ unsigned int h[NBINS];
  int t = threadIdx.x;
  int b = blockIdx.x >> 4, sub = blockIdx.x & 15;
  for (int p = t; p < NBINS; p += 256) h[p] = 0u;
  __syncthreads();
  const float* p = data + (size_t)b*S_ + (size_t)sub*16384;
  for (int k = 0; k < 64; ++k){
    float x = p[k*256 + t];
    int bin = (int)(x*BINSCALE);
    bin = min(max(bin, 0), NBINS-1);
    atomicAdd(&h[bin], 1u);
  }
  __syncthreads();
  unsigned int* hb = hist + (size_t)(b*16 + sub)*NBINS;
  for (int q = t; q < NBINS; q += 256) hb[q] = h[q];
}

// ---- pick order statistics: sum 16 partials, walk bins in registers ----
__global__ __launch_bounds__(256) void pick_hist_kernel(
    const unsigned int* __restrict__ hist, int r0, int r1, int r2, int r3,
    int nranks, float* __restrict__ outv, int which){
  __shared__ unsigned int part[256];
  __shared__ int s_own[4], s_rem[4];
  __shared__ float s_val[4];
  int t = threadIdx.x, b = blockIdx.x;
  const unsigned int* hb = hist + (size_t)b*16*NBINS;
  unsigned int binc[16];
  #pragma unroll
  for (int k = 0; k < 16; ++k) binc[k] = 0u;
  for (int sub = 0; sub < 16; ++sub){
    const unsigned int* hp = hb + (size_t)sub*NBINS + t*16;
    #pragma unroll
    for (int k = 0; k < 16; ++k) binc[k] += hp[k];
  }
  unsigned int sum = 0u;
  #pragma unroll
  for (int k = 0; k < 16; ++k) sum += binc[k];
  part[t] = sum;
  __syncthreads();
  if (t == 0){
    int rk[4] = {r0, r1, r2, r3};
    for (int ri = 0; ri < nranks; ++ri){
      int rem = rk[ri]; int own = 255;
      for (int q = 0; q < 256; ++q){
        if ((unsigned int)rem < part[q]){ own = q; break; }
        rem -= (int)part[q];
      }
      s_own[ri] = own; s_rem[ri] = rem;
    }
  }
  __syncthreads();
  for (int ri = 0; ri < nranks; ++ri){
    if (t == s_own[ri]){
      int rem = s_rem[ri]; int bin = t*16 + 15;
      #pragma unroll
      for (int q = 0; q < 16; ++q){
        if ((unsigned int)rem < binc[q]){ bin = t*16 + q; break; }
        rem -= (int)binc[q];
      }
      s_val[ri] = ((float)bin + 0.5f) * BINW;
    }
  }
  __syncthreads();
  if (t == 0){
    if (which == 0){
      outv[2*b+0] = s_val[0]*0.57f + s_val[1]*0.43f;   // lo (pos frac .43)
      outv[2*b+1] = s_val[2]*0.43f + s_val[3]*0.57f;   // hi (pos frac .57)
    } else {
      outv[b] = fmaxf(0.5f*(s_val[0] + s_val[1]), EPS_); // median -> sigma
    }
  }
}

// ---- N_hat + grad_mag (both stored) ----
__global__ __launch_bounds__(256) void nhat_gm_kernel(const float* __restrict__ x,
                                                      const float* __restrict__ vx2,
                                                      float* __restrict__ nh,
                                                      float* __restrict__ gm){
  int j = blockIdx.x*64 + threadIdx.x;
  int i = blockIdx.y*4 + threadIdx.y;
  int b = blockIdx.z;
  float lo = vx2[2*b], hi = vx2[2*b+1];
  float inv = 1.0f/(hi - lo + EPS_);
  size_t base = (size_t)b*S_ + (size_t)i*W_ + j;
  float c = fminf(fmaxf((x[base] - lo)*inv, 0.f), 1.f);
  float dx = 0.f, dy = 0.f;
  if (j < W_-1) dx = fminf(fmaxf((x[base+1]  - lo)*inv, 0.f), 1.f) - c;
  if (i < H_-1) dy = fminf(fmaxf((x[base+W_] - lo)*inv, 0.f), 1.f) - c;
  nh[base] = c;
  gm[base] = sqrtf(dx*dx + dy*dy + EPS_);
}

// ---- fused T-iteration primal-dual (hardware-proven version, verbatim) ----
#define TILE 48
#define NPIX (TILE*TILE)
#define CORE 32
#define HALO 8

#define AW_(d) (ALPHA_*(1.0f + MU_*__expf(-fabsf(d)*invs)))

__global__ __launch_bounds__(256, 4) void pd_fused_kernel(
    const float* __restrict__ u_in,  const float* __restrict__ ub_in,
    const float* __restrict__ px_in, const float* __restrict__ py_in,
    float* __restrict__ u_out,  float* __restrict__ ub_out,
    float* __restrict__ px_out, float* __restrict__ py_out,
    const float* __restrict__ nh_g, const float* __restrict__ sig_arr,
    int T, int mode)   // mode 1 = init from nh; 2 = last launch (store u only)
{
  __shared__ float sA[NPIX], sB[NPIX];
  const int t = threadIdx.x;
  const int b = blockIdx.z;
  const int gi0 = blockIdx.y*CORE - HALO;
  const int gj0 = blockIdx.x*CORE - HALO;
  const float invs = 1.0f / sig_arr[b];
  const int pi = t >> 4, pj = t & 15;
  const int r0 = 3*pi, c0 = 3*pj;
  const size_t bb = (size_t)b*S_;

  #define STAGE(dst, srcP, ZOOB)                                   \
    _Pragma("unroll")                                              \
    for (int k = 0; k < 9; ++k){                                   \
      int p = t + k*256; int li = p/TILE, lj = p - li*TILE;        \
      int gi = gi0+li, gj = gj0+lj;                                \
      int gic = min(max(gi,0),H_-1), gjc = min(max(gj,0),W_-1);    \
      float v = srcP[bb + (size_t)gic*W_ + gjc];                   \
      if (ZOOB && ((gi != gic) || (gj != gjc))) v = 0.f;           \
      dst[p] = v; }

  // Phase A: nh
  STAGE(sB, nh_g, 0)
  if (mode == 1){ STAGE(sA, nh_g, 0) }
  __syncthreads();

  float nh_r[9], ax[9], ay[9], axL[3], ayU[3];
  #pragma unroll
  for (int r = 0; r < 3; ++r)
  #pragma unroll
  for (int c = 0; c < 3; ++c){
    const int q = r*3+c, li = r0+r, lj = c0+c;
    const int gi = gi0+li, gj = gj0+lj;
    float nhc = sB[li*TILE+lj];
    float nhR = sB[li*TILE + min(lj+1,TILE-1)];
    float nhD = sB[min(li+1,TILE-1)*TILE + lj];
    nh_r[q] = nhc;
    ax[q] = (gj < 0 || gj >= W_-1) ? 0.f : AW_(nhR-nhc);
    ay[q] = (gi < 0 || gi >= H_-1) ? 0.f : AW_(nhD-nhc);
  }
  #pragma unroll
  for (int r = 0; r < 3; ++r){
    int liL = r0+r, gjL = gj0 + c0 - 1;
    int idxc = max(c0-1, 0);
    float nhc = sB[liL*TILE + idxc];
    float nhR = sB[liL*TILE + min(idxc+1,TILE-1)];
    axL[r] = (gjL < 0 || gjL >= W_-1) ? 0.f : AW_(nhR-nhc);
  }
  #pragma unroll
  for (int c = 0; c < 3; ++c){
    int giU = gi0 + r0 - 1;
    int idxr = max(r0-1, 0);
    float nhc = sB[idxr*TILE + c0+c];
    float nhD = sB[min(idxr+1,TILE-1)*TILE + c0+c];
    ayU[c] = (giU < 0 || giU >= H_-1) ? 0.f : AW_(nhD-nhc);
  }
  __syncthreads();

  float u_r[9], ub_r[9], px_r[9], py_r[9], pxL[3], pyU[3];
  if (mode == 1){
    #pragma unroll
    for (int q = 0; q < 9; ++q){ u_r[q] = nh_r[q]; ub_r[q] = nh_r[q]; px_r[q] = 0.f; py_r[q] = 0.f; }
    pxL[0]=pxL[1]=pxL[2]=0.f; pyU[0]=pyU[1]=pyU[2]=0.f;
    // sA already holds nh = initial ub
  } else {
    STAGE(sB, u_in, 0)
    __syncthreads();
    #pragma unroll
    for (int q = 0; q < 9; ++q) u_r[q] = sB[(r0+q/3)*TILE + c0 + q%3];
    __syncthreads();
    STAGE(sB, px_in, 1)
    __syncthreads();
    #pragma unroll
    for (int q = 0; q < 9; ++q) px_r[q] = sB[(r0+q/3)*TILE + c0 + q%3];
    #pragma unroll
    for (int r = 0; r < 3; ++r) pxL[r] = sB[(r0+r)*TILE + max(c0-1,0)];
    __syncthreads();
    STAGE(sB, py_in, 1)
    __syncthreads();
    #pragma unroll
    for (int q = 0; q < 9; ++q) py_r[q] = sB[(r0+q/3)*TILE + c0 + q%3];
    #pragma unroll
    for (int c = 0; c < 3; ++c) pyU[c] = sB[max(r0-1,0)*TILE + c0+c];
    __syncthreads();
    STAGE(sA, ub_in, 0)
    __syncthreads();
    #pragma unroll
    for (int q = 0; q < 9; ++q) ub_r[q] = sA[(r0+q/3)*TILE + c0 + q%3];
  }

  for (int s = 0; s < T; ++s){
    float* RB = (s & 1) ? sB : sA;
    float* WB = (s & 1) ? sA : sB;
    float ubL[3], ubR[3], ubU[3], ubD[3];
    #pragma unroll
    for (int r = 0; r < 3; ++r){
      ubL[r] = RB[(r0+r)*TILE + max(c0-1,0)];
      ubR[r] = RB[(r0+r)*TILE + min(c0+3,TILE-1)];
    }
    #pragma unroll
    for (int c = 0; c < 3; ++c){
      ubU[c] = RB[max(r0-1,0)*TILE + c0+c];
      ubD[c] = RB[min(r0+3,TILE-1)*TILE + c0+c];
    }
    #pragma unroll
    for (int r = 0; r < 3; ++r)
      pxL[r] = fminf(fmaxf(fmaf(SIG_, ub_r[r*3] - ubL[r], pxL[r]), -axL[r]), axL[r]);
    #pragma unroll
    for (int c = 0; c < 3; ++c)
      pyU[c] = fminf(fmaxf(fmaf(SIG_, ub_r[c] - ubU[c], pyU[c]), -ayU[c]), ayU[c]);
    #pragma unroll
    for (int r = 0; r < 3; ++r)
    #pragma unroll
    for (int c = 0; c < 3; ++c){
      const int q = r*3+c;
      float ubRn = (c < 2) ? ub_r[q+1] : ubR[r];
      float ubDn = (r < 2) ? ub_r[q+3] : ubD[c];
      px_r[q] = fminf(fmaxf(fmaf(SIG_, ubRn - ub_r[q], px_r[q]), -ax[q]), ax[q]);
      py_r[q] = fminf(fmaxf(fmaf(SIG_, ubDn - ub_r[q], py_r[q]), -ay[q]), ay[q]);
    }
    #pragma unroll
    for (int r = 0; r < 3; ++r)
    #pragma unroll
    for (int c = 0; c < 3; ++c){
      const int q = r*3+c;
      float pxln = (c > 0) ? px_r[q-1] : pxL[r];
      float pyun = (r > 0) ? py_r[q-3] : pyU[c];
      float div = px_r[q] + py_r[q] - pxln - pyun;
      float un = fmaf(TAU_, div + nh_r[q], u_r[q]) * INV1PT_;
      float ubn = 2.f*un - u_r[q];
      u_r[q] = un; ub_r[q] = ubn;
      WB[(r0+r)*TILE + c0+c] = ubn;
    }
    __syncthreads();
  }

  #pragma unroll
  for (int r = 0; r < 3; ++r)
  #pragma unroll
  for (int c = 0; c < 3; ++c){
    const int q = r*3+c, li = r0+r, lj = c0+c;
    if (li >= HALO && li < HALO+CORE && lj >= HALO && lj < HALO+CORE){
      size_t g = bb + (size_t)(gi0+li)*W_ + (gj0+lj);
      u_out[g] = u_r[q];
      if (mode != 2){
        ub_out[g] = ub_r[q];
        px_out[g] = px_r[q];
        py_out[g] = py_r[q];
      }
    }
  }
}

// ---- final clip ----
__global__ __launch_bounds__(256) void final_kernel(const float* __restrict__ u,
                                                    float* __restrict__ out){
  size_t idx = (size_t)blockIdx.x*256 + threadIdx.x;
  if (idx < (size_t)B_*S_) out[idx] = fminf(fmaxf(u[idx], 0.f), 1.f);
}

extern "C" void kernel_launch(void* const* d_in, const int* in_sizes, int n_in,
                              void* d_out, int out_size, void* d_ws, size_t ws_size,
                              hipStream_t stream){
  const float* Iy = (const float*)d_in[0];
  float* out = (float*)d_out;
  char* ws = (char*)d_ws;
  const size_t SLOT = (size_t)B_*S_*sizeof(float);
  float* slot[8];
  for (int q = 0; q < 8; ++q) slot[q] = (float*)(ws + (size_t)q*SLOT);
  float* vx2 = (float*)(ws + (size_t)8*SLOT);  // lo,hi per batch (32 floats)
  float* sig = vx2 + 32;                       // sigma per batch (16 floats)

  // slot lifetimes: s0 Rh->gm->pyB  s1 GBh->uA  s2 x->ubA  s3 pxA
  // s4 partial histograms->pyA  s5 Rf->uB  s6 Gf->ubB  s7 pxB ; nh in d_out.
  float* Rh  = slot[0];
  float* GBh = slot[1];
  float* Rf  = slot[5];
  float* Gf  = slot[6];
  float* xb  = slot[2];
  float* gm  = slot[0];
  float* nh  = out;
  float* uu[2]  = { slot[1], slot[5] };
  float* ubb[2] = { slot[2], slot[6] };
  float* pxx[2] = { slot[3], slot[7] };
  float* pyy[2] = { slot[4], slot[0] };

  // partial histograms inside slot4 (16 MiB; 2 stats x 256 blocks x 4096 bins
  // x 4 B = 8 MiB; consumed before PD L0 writes pyy[0]). All bins written
  // unconditionally by hist_build -> no memset needed.
  unsigned int* hist_x  = (unsigned int*)(ws + (size_t)4*SLOT);          // 4 MiB
  unsigned int* hist_gm = hist_x + (size_t)256*NBINS;                    // 4 MiB

  dim3 blk(64, 4, 1), grd(W_/64, H_/4, B_);

  hmax_kernel<<<B_*H_, 256, 0, stream>>>(Iy, Rh, GBh);
  vscan_fwd_kernel<<<288, 256, 0, stream>>>(Rh, GBh, Rf, Gf);
  vscan_bwd_kernel<<<288, 256, 0, stream>>>(Rh, GBh, Rf, Gf, Iy, xb);
  hist_build_kernel<<<256, 256, 0, stream>>>(xb, hist_x);
  // ranks: floor/ceil of 0.01*(N-1)=2621.43 and 0.99*(N-1)=259521.57
  pick_hist_kernel<<<B_, 256, 0, stream>>>(hist_x, 2621, 2622, 259521, 259522, 4, vx2, 0);
  nhat_gm_kernel<<<grd, blk, 0, stream>>>(xb, vx2, nh, gm);
  hist_build_kernel<<<256, 256, 0, stream>>>(gm, hist_gm);
  // median ranks 131071, 131072
  pick_hist_kernel<<<B_, 256, 0, stream>>>(hist_gm, 131071, 131072, 0, 0, 2, sig, 1);

  dim3 pdg(W_/CORE, H_/CORE, B_);
  pd_fused_kernel<<<pdg, 256, 0, stream>>>(nh, nh, nh, nh,
                                           uu[0], ubb[0], pxx[0], pyy[0],
                                           nh, sig, 8, 1);
  pd_fused_kernel<<<pdg, 256, 0, stream>>>(uu[0], ubb[0], pxx[0], pyy[0],
                                           uu[1], ubb[1], pxx[1], pyy[1],
                                           nh, sig, 8, 0);
  pd_fused_kernel<<<pdg, 256, 0, stream>>>(uu[1], ubb[1], pxx[1], pyy[1],
                                           uu[0], ubb[0], pxx[0], pyy[0],
                                           nh, sig, 8, 0);
  pd_fused_kernel<<<pdg, 256, 0, stream>>>(uu[0], ubb[0], pxx[0], pyy[0],
                                           uu[1], ubb[1], pxx[1], pyy[1],
                                           nh, sig, 6, 2);

  int total = B_*S_;
  final_kernel<<<(total+255)/256, 256, 0, stream>>>(uu[1], out);
}